// Round 10
// baseline (299.765 us; speedup 1.0000x reference)
//
#include <hip/hip_runtime.h>
#include <cstddef>
#include <cstdint>

namespace {

typedef __fp16 h2v __attribute__((ext_vector_type(2)));

constexpr int kB = 4096, kT = 1024, kI = 8, kH = 12, kA = 4;
constexpr int kTC = 32;               // timesteps per staged chunk
constexpr int kNCH = kT / kTC;        // 32 chunks
constexpr int kWaveU = 256;           // 2 elements * 128 uints per wave
constexpr int kBlkU  = 4 * kWaveU;    // 1024 uints per buffer

constexpr float kL2E  = 1.442695041f;   // log2(e)
constexpr float kL2E2 = 2.885390082f;   // 2*log2(e)

template<int N>
__device__ __forceinline__ uint32_t ror16u(uint32_t v) {
    return (uint32_t)__builtin_amdgcn_mov_dpp((int)v, 0x120 + N, 0xF, 0xF, false);
}
__device__ __forceinline__ float ror16f1(float v) {
    return __int_as_float(__builtin_amdgcn_mov_dpp(__float_as_int(v), 0x121, 0xF, 0xF, false));
}
__device__ __forceinline__ float bperm(int byte_addr, float v) {
    return __int_as_float(__builtin_amdgcn_ds_bpermute(byte_addr, __float_as_int(v)));
}
__device__ __forceinline__ uint32_t pkrtz(float lo, float hi) {
    auto v = __builtin_amdgcn_cvt_pkrtz(lo, hi);
    return __builtin_bit_cast(uint32_t, v);
}
__device__ __forceinline__ h2v uh(uint32_t u) { return __builtin_bit_cast(h2v, u); }

#if __has_builtin(__builtin_amdgcn_permlane32_swap)
#define USE_PLSWAP 1
// Compiler-known half-exchange (gfx950, HW-verified in learn_hip T12/m255).
// With a==b==v the two results are {lo-half broadcast, hi-half broadcast} in
// an order resolved at runtime by the caller's probe.
__device__ __forceinline__ void xhalf(float v, float& r0, float& r1) {
    auto r = __builtin_amdgcn_permlane32_swap(__float_as_int(v), __float_as_int(v),
                                              false, false);
    r0 = __int_as_float(r[0]);
    r1 = __int_as_float(r[1]);
}
#else
#define USE_PLSWAP 0
#endif

__global__ __launch_bounds__(256, 2)
void lstm_fused_kernel(const float* __restrict__ x,
                       const float* __restrict__ W_ih,
                       const float* __restrict__ W_hh,
                       const float* __restrict__ b_ih,
                       const float* __restrict__ b_hh,
                       const float* __restrict__ W_fc,
                       const float* __restrict__ b_fc,
                       float* __restrict__ out) {
    __shared__ uint32_t xs[2][kBlkU];   // staged x (f16 pairs), double-buffered, wave-private

    const int tid = threadIdx.x;
    const int wv  = tid >> 6;           // wave in block
    const int l64 = tid & 63;           // lane in wave
    const int ri  = l64 >> 4;           // 16-row 0..3
    const int r   = l64 & 15;           // unit index within row
    const int e   = ri & 1;             // element (rows 0,2: elem0; rows 1,3: elem1)
    const int gh  = ri >> 1;            // 0: (i,f) rows [+FC] (lanes<32), 1: (g,o) rows
    const int b0  = blockIdx.x * 8 + wv * 2;
    const int b   = b0 + e;
    const bool isFC = (gh == 0) && (r >= kH);
    const int a  = isFC ? (r - kH) : 0;

    // DPP row_ror direction probe (r5/r6/r7-proven)
    const int probe = __builtin_amdgcn_mov_dpp(r, 0x121, 0xF, 0xF, false);
    const int dir   = (probe - r) & 15;

#if USE_PLSWAP
    // Direction probe for the half-exchange: r0lo == "result0 is the lanes<32
    // broadcast". Uniform under either half-ordering.
    bool r0lo;
    {
        float t0, t1;
        xhalf((l64 < 32) ? 0.0f : 1.0f, t0, t1);
        r0lo = (t0 == 0.0f);
    }
#endif

    // ---- packed f16 weights; h-cols pre-rotated & paired to the Q-rotation ----
    h2v w1p[8], w2p[8], x1p[4], x2p[4];
    float b1, b2;
    if (r < kH) {
        const int row1 = (gh == 0) ? r : (2 * kH + r);          // i or g
        const int row2 = (gh == 0) ? (kH + r) : (3 * kH + r);   // f or o
        const float scl1 = (gh == 0) ? -kL2E : -kL2E2;
        const float scl2 = -kL2E;
#pragma unroll
        for (int j = 0; j < 8; ++j) {
            const int c0 = (r + dir * 2 * j) & 15;
            const int cc = (c0 + dir) & 15;
            const float u0 = (c0 < kH) ? W_hh[row1 * kH + c0] : 0.0f;
            const float u1 = (cc < kH) ? W_hh[row1 * kH + cc] : 0.0f;
            const float v0 = (c0 < kH) ? W_hh[row2 * kH + c0] : 0.0f;
            const float v1 = (cc < kH) ? W_hh[row2 * kH + cc] : 0.0f;
            w1p[j] = h2v{(__fp16)(scl1 * u0), (__fp16)(scl1 * u1)};
            w2p[j] = h2v{(__fp16)(scl2 * v0), (__fp16)(scl2 * v1)};
        }
#pragma unroll
        for (int i2 = 0; i2 < 4; ++i2) {
            x1p[i2] = h2v{(__fp16)(scl1 * W_ih[row1 * kI + 2 * i2]),
                          (__fp16)(scl1 * W_ih[row1 * kI + 2 * i2 + 1])};
            x2p[i2] = h2v{(__fp16)(scl2 * W_ih[row2 * kI + 2 * i2]),
                          (__fp16)(scl2 * W_ih[row2 * kI + 2 * i2 + 1])};
        }
        b1 = scl1 * (b_ih[row1] + b_hh[row1]);
        b2 = scl2 * (b_ih[row2] + b_hh[row2]);
    } else if (gh == 0) {   // FC lane: unscaled (stores s1 pre-activation)
#pragma unroll
        for (int j = 0; j < 8; ++j) {
            const int c0 = (r + dir * 2 * j) & 15;
            const int cc = (c0 + dir) & 15;
            const float u0 = (c0 < kH) ? W_fc[a * kH + c0] : 0.0f;
            const float u1 = (cc < kH) ? W_fc[a * kH + cc] : 0.0f;
            w1p[j] = h2v{(__fp16)u0, (__fp16)u1};
            w2p[j] = h2v{(__fp16)0.f, (__fp16)0.f};
        }
#pragma unroll
        for (int i2 = 0; i2 < 4; ++i2) {
            x1p[i2] = h2v{(__fp16)0.f, (__fp16)0.f};
            x2p[i2] = h2v{(__fp16)0.f, (__fp16)0.f};
        }
        b1 = b_fc[a]; b2 = 0.0f;
    } else {                // (g,o)-side pad lanes: h stays exactly 0
#pragma unroll
        for (int j = 0; j < 8; ++j) { w1p[j] = h2v{(__fp16)0.f, (__fp16)0.f}; w2p[j] = w1p[j]; }
#pragma unroll
        for (int i2 = 0; i2 < 4; ++i2) { x1p[i2] = h2v{(__fp16)0.f, (__fp16)0.f}; x2p[i2] = x1p[i2]; }
        b1 = 0.0f; b2 = 0.0f;
    }
    const float m1  = (gh == 0) ? 1.0f : 2.0f;
    const float a1c = (gh == 0) ? 0.0f : -1.0f;
#if !USE_PLSWAP
    const int exa = (l64 ^ 32) << 2;    // bpermute partner address (r7-proven fallback)
#endif

    // ---- x staging: f32 global -> f16 pairs in LDS (wave-private, fence-ordered) ----
    const float* xga = x + (size_t)b0 * (kT * kI);
    const float* xgb = xga + (size_t)kT * kI;
    const int wbu = wv * kWaveU;
    const int rbu = wbu + e * 128;

    float4 rva = ((const float4*)xga)[l64];
    float4 rvb = ((const float4*)xgb)[l64];
    {
        uint2 ua; ua.x = pkrtz(rva.x, rva.y); ua.y = pkrtz(rva.z, rva.w);
        uint2 ub; ub.x = pkrtz(rvb.x, rvb.y); ub.y = pkrtz(rvb.z, rvb.w);
        *(uint2*)&xs[0][wbu + l64 * 2]       = ua;
        *(uint2*)&xs[0][wbu + 128 + l64 * 2] = ub;
    }
    asm volatile("s_waitcnt lgkmcnt(0)" ::: "memory");
    __builtin_amdgcn_sched_barrier(0);
    uint4 xr = *(const uint4*)&xs[0][rbu];

    float h = 0.0f, c = 0.0f;
    uint32_t hrp[8];
#pragma unroll
    for (int k = 0; k < 8; ++k) hrp[k] = 0u;

    float* op = out + (size_t)b * (kT * kA) + a;

    int cb = 0;
#pragma unroll 1
    for (int ch = 0; ch < kNCH; ++ch) {
        if (ch + 1 < kNCH) {   // issue next chunk's global loads early
            rva = ((const float4*)(xga + (size_t)(ch + 1) * (kTC * kI)))[l64];
            rvb = ((const float4*)(xgb + (size_t)(ch + 1) * (kTC * kI)))[l64];
        }
#pragma unroll 2
        for (int tt = 0; tt < kTC; ++tt) {
            // two gate dots: 16 fdot2 over paired h + 8 over x (fp32 accum)
            float s1 = b1, s2 = b2;
#pragma unroll
            for (int j = 0; j < 8; ++j) {
                const h2v hv = uh(hrp[j]);
                s1 = __builtin_amdgcn_fdot2(w1p[j], hv, s1, false);
                s2 = __builtin_amdgcn_fdot2(w2p[j], hv, s2, false);
            }
            s1 = __builtin_amdgcn_fdot2(x1p[0], uh(xr.x), s1, false);
            s2 = __builtin_amdgcn_fdot2(x2p[0], uh(xr.x), s2, false);
            s1 = __builtin_amdgcn_fdot2(x1p[1], uh(xr.y), s1, false);
            s2 = __builtin_amdgcn_fdot2(x2p[1], uh(xr.y), s2, false);
            s1 = __builtin_amdgcn_fdot2(x1p[2], uh(xr.z), s1, false);
            s2 = __builtin_amdgcn_fdot2(x2p[2], uh(xr.z), s2, false);
            s1 = __builtin_amdgcn_fdot2(x1p[3], uh(xr.w), s1, false);
            s2 = __builtin_amdgcn_fdot2(x2p[3], uh(xr.w), s2, false);
            // prefetch next step's x (broadcast read, off critical path)
            if (tt + 1 < kTC) xr = *(const uint4*)&xs[cb][rbu + (tt + 1) * 4];
            // FC lanes: s1 = wfc.h_{t-1} + b_fc = out[t-1] (delayed store)
            if ((ch | tt) != 0) { if (isFC) op[-kA] = s1; }
            // activations (scale pre-folded into weights)
            const float e1   = __builtin_amdgcn_exp2f(s1);
            const float act1 = fmaf(m1, __builtin_amdgcn_rcpf(1.0f + e1), a1c); // i | g
            const float e2   = __builtin_amdgcn_exp2f(s2);
            const float act2 = __builtin_amdgcn_rcpf(1.0f + e2);                // f | o
            // cross-half exchange -> gate broadcasts on all lanes
            float q0, q1, t0, t1;
#if USE_PLSWAP
            xhalf(act1, q0, q1);                // {i-bcast, g-bcast} in probe order
            xhalf(act2, t0, t1);                // {f-bcast, o-bcast} in probe order
            const float ig = q0 * q1;           // order-independent
            const float fv = r0lo ? t0 : t1;
            const float ov = r0lo ? t1 : t0;
#else
            const float o1 = bperm(exa, act1);  // partner act1
            const float o2 = bperm(exa, act2);  // partner act2
            const float ig = act1 * o1;
            const float fv = (gh == 0) ? act2 : o2;
            const float ov = (gh == 0) ? o2 : act2;
            (void)q0; (void)q1; (void)t0; (void)t1;
#endif
            // state update (uniform on all lanes)
            c = fmaf(fv, c, ig);
            const float ec = __builtin_amdgcn_exp2f(-kL2E2 * c);
            const float tc = fmaf(2.0f, __builtin_amdgcn_rcpf(1.0f + ec), -1.0f);
            h = ov * tc;
            // packed h broadcast: Q = (h_r, h_{r+dir}); one DPP rotate = two h values
            const float hn1 = ror16f1(h);
            const uint32_t Q = pkrtz(h, hn1);
            hrp[0] = Q;
            hrp[1] = ror16u<2>(Q);
            hrp[2] = ror16u<4>(Q);
            hrp[3] = ror16u<6>(Q);
            hrp[4] = ror16u<8>(Q);
            hrp[5] = ror16u<10>(Q);
            hrp[6] = ror16u<12>(Q);
            hrp[7] = ror16u<14>(Q);
            op += kA;
        }
        if (ch + 1 < kNCH) {   // late LDS write of prefetched chunk + fence
            const int nb = cb ^ 1;
            uint2 ua; ua.x = pkrtz(rva.x, rva.y); ua.y = pkrtz(rva.z, rva.w);
            uint2 ub; ub.x = pkrtz(rvb.x, rvb.y); ub.y = pkrtz(rvb.z, rvb.w);
            *(uint2*)&xs[nb][wbu + l64 * 2]       = ua;
            *(uint2*)&xs[nb][wbu + 128 + l64 * 2] = ub;
            asm volatile("s_waitcnt lgkmcnt(0)" ::: "memory");
            __builtin_amdgcn_sched_barrier(0);
            xr = *(const uint4*)&xs[nb][rbu];
            cb = nb;
        }
    }

    {   // epilogue: out[T-1] = wfc . h_{T-1} + b_fc
        float s1 = b1;
#pragma unroll
        for (int j = 0; j < 8; ++j)
            s1 = __builtin_amdgcn_fdot2(w1p[j], uh(hrp[j]), s1, false);
        if (isFC) op[-kA] = s1;
    }
    if (gh == 0 && r < kH) {   // hn, cn (fp32 master state)
        float* hn = out + (size_t)kB * kT * kA;
        hn[(size_t)b * kH + r] = h;
        hn[(size_t)kB * kH + (size_t)b * kH + r] = c;
    }
}

}  // namespace

extern "C" void kernel_launch(void* const* d_in, const int* in_sizes, int n_in,
                              void* d_out, int out_size, void* d_ws, size_t ws_size,
                              hipStream_t stream) {
    (void)in_sizes; (void)n_in; (void)d_ws; (void)ws_size; (void)out_size;
    const float* x    = (const float*)d_in[0];
    const float* W_ih = (const float*)d_in[1];
    const float* W_hh = (const float*)d_in[2];
    const float* b_ih = (const float*)d_in[3];
    const float* b_hh = (const float*)d_in[4];
    const float* W_fc = (const float*)d_in[5];
    const float* b_fc = (const float*)d_in[6];
    float* out = (float*)d_out;
    hipLaunchKernelGGL(lstm_fused_kernel, dim3(kB / 8), dim3(256), 0, stream,
                       x, W_ih, W_hh, b_ih, b_hh, W_fc, b_fc, out);
}

// Round 11
// 246.711 us; speedup vs baseline: 1.2150x; 1.2150x over previous
//
#include <hip/hip_runtime.h>
#include <cstddef>
#include <cstdint>

namespace {

typedef __fp16 h2v __attribute__((ext_vector_type(2)));

constexpr int kB = 4096, kT = 1024, kI = 8, kH = 12, kA = 4;
constexpr int kTC  = 32;               // timesteps per staged chunk
constexpr int kNCH = kT / kTC;         // 32 chunks
constexpr int kXRegU = 132;            // 128 payload uints + 4 pad (bank stagger across groups)
constexpr int kBlkU  = 16 * kXRegU;    // 16 elements per block

constexpr float kL2E  = 1.442695041f;   // log2(e)
constexpr float kL2E2 = 2.885390082f;   // 2*log2(e)

template<int N>
__device__ __forceinline__ uint32_t ror16u(uint32_t v) {
    return (uint32_t)__builtin_amdgcn_mov_dpp((int)v, 0x120 + N, 0xF, 0xF, false);
}
__device__ __forceinline__ float ror16f1(float v) {
    return __int_as_float(__builtin_amdgcn_mov_dpp(__float_as_int(v), 0x121, 0xF, 0xF, false));
}
__device__ __forceinline__ uint32_t pkrtz(float lo, float hi) {
    auto v = __builtin_amdgcn_cvt_pkrtz(lo, hi);
    return __builtin_bit_cast(uint32_t, v);
}
__device__ __forceinline__ h2v uh(uint32_t u) { return __builtin_bit_cast(h2v, u); }

__global__ __launch_bounds__(256, 1)
void lstm_fused_kernel(const float* __restrict__ x,
                       const float* __restrict__ W_ih,
                       const float* __restrict__ W_hh,
                       const float* __restrict__ b_ih,
                       const float* __restrict__ b_hh,
                       const float* __restrict__ W_fc,
                       const float* __restrict__ b_fc,
                       float* __restrict__ out) {
    __shared__ uint32_t xs[2][kBlkU];   // staged x (f16 pairs), double-buffered, wave-private

    const int tid = threadIdx.x;
    const int wv  = tid >> 6;           // wave in block
    const int l64 = tid & 63;           // lane in wave
    const int grp = l64 >> 4;           // 16-lane group == DPP row == element
    const int r   = l64 & 15;           // unit index within element (12..15 = FC rows)
    const int ei  = wv * 4 + grp;       // element index within block
    const int b   = blockIdx.x * 16 + ei;
    const bool isFC = (r >= kH);
    const int a   = isFC ? (r - kH) : 0;

    // DPP row_ror direction probe (r5/r6/r7-proven)
    const int probe = __builtin_amdgcn_mov_dpp(r, 0x121, 0xF, 0xF, false);
    const int dir   = (probe - r) & 15;

    // ---- packed f16 weights, all 4 gates per lane; h-cols pre-rotated & paired ----
    // hrp[j] = (h_c0, h_c1), c0=(r+dir*2j)&15, c1=(c0+dir)&15  (r7-proven pairing)
    h2v wp[4][8], xp[4][4];
    float bs[4];
    if (!isFC) {
#pragma unroll
        for (int g = 0; g < 4; ++g) {              // PyTorch gate order i,f,g,o
            const int row = g * kH + r;
            const float scl = (g == 2) ? -kL2E2 : -kL2E;   // tanh row gets 2*log2e
#pragma unroll
            for (int jj = 0; jj < 8; ++jj) {
                const int c0 = (r + dir * 2 * jj) & 15;
                const int c1 = (c0 + dir) & 15;
                const float u0 = (c0 < kH) ? W_hh[row * kH + c0] : 0.0f;
                const float u1 = (c1 < kH) ? W_hh[row * kH + c1] : 0.0f;
                wp[g][jj] = h2v{(__fp16)(scl * u0), (__fp16)(scl * u1)};
            }
#pragma unroll
            for (int i2 = 0; i2 < 4; ++i2)
                xp[g][i2] = h2v{(__fp16)(scl * W_ih[row * kI + 2 * i2]),
                                (__fp16)(scl * W_ih[row * kI + 2 * i2 + 1])};
            bs[g] = scl * (b_ih[row] + b_hh[row]);
        }
    } else {   // FC lane: gate0 = W_fc row (unscaled, pre-activation output); gates 1-3 zero
#pragma unroll
        for (int jj = 0; jj < 8; ++jj) {
            const int c0 = (r + dir * 2 * jj) & 15;
            const int c1 = (c0 + dir) & 15;
            const float u0 = (c0 < kH) ? W_fc[a * kH + c0] : 0.0f;
            const float u1 = (c1 < kH) ? W_fc[a * kH + c1] : 0.0f;
            wp[0][jj] = h2v{(__fp16)u0, (__fp16)u1};
            wp[1][jj] = h2v{(__fp16)0.f, (__fp16)0.f};
            wp[2][jj] = wp[1][jj];
            wp[3][jj] = wp[1][jj];
        }
#pragma unroll
        for (int i2 = 0; i2 < 4; ++i2) {
            xp[0][i2] = h2v{(__fp16)0.f, (__fp16)0.f};
            xp[1][i2] = xp[0][i2]; xp[2][i2] = xp[0][i2]; xp[3][i2] = xp[0][i2];
        }
        bs[0] = b_fc[a]; bs[1] = 0.0f; bs[2] = 0.0f; bs[3] = 0.0f;
        // f=sig(0)=0.5, g=tanh(0)=0, o=0.5 -> c,h stay EXACTLY 0 on FC lanes,
        // so the zero-padded rotation columns (12..15) are exact.
    }

    // ---- x staging: each group stages its own element (f32 global -> f16 LDS) ----
    const float* xg = x + (size_t)b * (kT * kI);
    const int reg = ei * kXRegU;        // element region base (uints)

    float4 rv0, rv1, rv2, rv3;
    {   // prologue: chunk 0 -> buffer 0
        const float4* gp = (const float4*)xg;
        rv0 = gp[r]; rv1 = gp[16 + r]; rv2 = gp[32 + r]; rv3 = gp[48 + r];
        uint2 u;
        u.x = pkrtz(rv0.x, rv0.y); u.y = pkrtz(rv0.z, rv0.w);
        *(uint2*)&xs[0][reg + 2 * r] = u;
        u.x = pkrtz(rv1.x, rv1.y); u.y = pkrtz(rv1.z, rv1.w);
        *(uint2*)&xs[0][reg + 32 + 2 * r] = u;
        u.x = pkrtz(rv2.x, rv2.y); u.y = pkrtz(rv2.z, rv2.w);
        *(uint2*)&xs[0][reg + 64 + 2 * r] = u;
        u.x = pkrtz(rv3.x, rv3.y); u.y = pkrtz(rv3.z, rv3.w);
        *(uint2*)&xs[0][reg + 96 + 2 * r] = u;
    }
    asm volatile("s_waitcnt lgkmcnt(0)" ::: "memory");
    __builtin_amdgcn_sched_barrier(0);
    uint4 xr = *(const uint4*)&xs[0][reg];   // step 0: 8 f16

    float h = 0.0f, c = 0.0f;
    uint32_t hrp[8];
#pragma unroll
    for (int k = 0; k < 8; ++k) hrp[k] = 0u;

    float* op = out + (size_t)b * (kT * kA) + a;

    int cb = 0;
#pragma unroll 1
    for (int ch = 0; ch < kNCH; ++ch) {
        if (ch + 1 < kNCH) {   // issue next chunk's global loads early
            const float4* gp = (const float4*)(xg + (size_t)(ch + 1) * (kTC * kI));
            rv0 = gp[r]; rv1 = gp[16 + r]; rv2 = gp[32 + r]; rv3 = gp[48 + r];
        }
#pragma unroll 2
        for (int tt = 0; tt < kTC; ++tt) {
            // prefetch next step's x FIRST (max slack before use)
            uint4 xrn;
            if (tt + 1 < kTC) xrn = *(const uint4*)&xs[cb][reg + (tt + 1) * 4];
            // 4 gate dots: 32 fdot2 over paired h + 16 over x (fp32 accum)
            float s0 = bs[0], s1 = bs[1], s2 = bs[2], s3 = bs[3];
#pragma unroll
            for (int jj = 0; jj < 8; ++jj) {
                const h2v hv = uh(hrp[jj]);
                s0 = __builtin_amdgcn_fdot2(wp[0][jj], hv, s0, false);
                s1 = __builtin_amdgcn_fdot2(wp[1][jj], hv, s1, false);
                s2 = __builtin_amdgcn_fdot2(wp[2][jj], hv, s2, false);
                s3 = __builtin_amdgcn_fdot2(wp[3][jj], hv, s3, false);
            }
            {
                const h2v xv0 = uh(xr.x), xv1 = uh(xr.y), xv2 = uh(xr.z), xv3 = uh(xr.w);
                s0 = __builtin_amdgcn_fdot2(xp[0][0], xv0, s0, false);
                s1 = __builtin_amdgcn_fdot2(xp[1][0], xv0, s1, false);
                s2 = __builtin_amdgcn_fdot2(xp[2][0], xv0, s2, false);
                s3 = __builtin_amdgcn_fdot2(xp[3][0], xv0, s3, false);
                s0 = __builtin_amdgcn_fdot2(xp[0][1], xv1, s0, false);
                s1 = __builtin_amdgcn_fdot2(xp[1][1], xv1, s1, false);
                s2 = __builtin_amdgcn_fdot2(xp[2][1], xv1, s2, false);
                s3 = __builtin_amdgcn_fdot2(xp[3][1], xv1, s3, false);
                s0 = __builtin_amdgcn_fdot2(xp[0][2], xv2, s0, false);
                s1 = __builtin_amdgcn_fdot2(xp[1][2], xv2, s1, false);
                s2 = __builtin_amdgcn_fdot2(xp[2][2], xv2, s2, false);
                s3 = __builtin_amdgcn_fdot2(xp[3][2], xv2, s3, false);
                s0 = __builtin_amdgcn_fdot2(xp[0][3], xv3, s0, false);
                s1 = __builtin_amdgcn_fdot2(xp[1][3], xv3, s1, false);
                s2 = __builtin_amdgcn_fdot2(xp[2][3], xv3, s2, false);
                s3 = __builtin_amdgcn_fdot2(xp[3][3], xv3, s3, false);
            }
            // FC lanes: s0 = wfc.h_{t-1} + b_fc = out[t-1] (delayed store)
            if ((ch | tt) != 0) { if (isFC) op[-kA] = s0; }
            // activations (scales pre-folded into weights/biases)
            const float iv = __builtin_amdgcn_rcpf(1.0f + __builtin_amdgcn_exp2f(s0));
            const float fv = __builtin_amdgcn_rcpf(1.0f + __builtin_amdgcn_exp2f(s1));
            const float gv = fmaf(2.0f, __builtin_amdgcn_rcpf(1.0f + __builtin_amdgcn_exp2f(s2)), -1.0f);
            const float ov = __builtin_amdgcn_rcpf(1.0f + __builtin_amdgcn_exp2f(s3));
            // state update — fully in-lane, no cross-lane exchange
            c = fmaf(fv, c, iv * gv);
            const float ec = __builtin_amdgcn_exp2f(-kL2E2 * c);
            const float tc = fmaf(2.0f, __builtin_amdgcn_rcpf(1.0f + ec), -1.0f);
            h = ov * tc;
            // packed h broadcast: Q = (h_r, h_{r+dir}); one DPP rotate = two h values
            const float hn1 = ror16f1(h);
            const uint32_t Q = pkrtz(h, hn1);
            hrp[0] = Q;
            hrp[1] = ror16u<2>(Q);
            hrp[2] = ror16u<4>(Q);
            hrp[3] = ror16u<6>(Q);
            hrp[4] = ror16u<8>(Q);
            hrp[5] = ror16u<10>(Q);
            hrp[6] = ror16u<12>(Q);
            hrp[7] = ror16u<14>(Q);
            if (tt + 1 < kTC) xr = xrn;
            op += kA;
        }
        if (ch + 1 < kNCH) {   // late LDS write of prefetched chunk + fence
            const int nb = cb ^ 1;
            uint2 u;
            u.x = pkrtz(rv0.x, rv0.y); u.y = pkrtz(rv0.z, rv0.w);
            *(uint2*)&xs[nb][reg + 2 * r] = u;
            u.x = pkrtz(rv1.x, rv1.y); u.y = pkrtz(rv1.z, rv1.w);
            *(uint2*)&xs[nb][reg + 32 + 2 * r] = u;
            u.x = pkrtz(rv2.x, rv2.y); u.y = pkrtz(rv2.z, rv2.w);
            *(uint2*)&xs[nb][reg + 64 + 2 * r] = u;
            u.x = pkrtz(rv3.x, rv3.y); u.y = pkrtz(rv3.z, rv3.w);
            *(uint2*)&xs[nb][reg + 96 + 2 * r] = u;
            asm volatile("s_waitcnt lgkmcnt(0)" ::: "memory");
            __builtin_amdgcn_sched_barrier(0);
            xr = *(const uint4*)&xs[nb][reg];
            cb = nb;
        }
    }

    {   // epilogue: out[T-1] = wfc . h_{T-1} + b_fc
        float s0 = bs[0];
#pragma unroll
        for (int jj = 0; jj < 8; ++jj)
            s0 = __builtin_amdgcn_fdot2(wp[0][jj], uh(hrp[jj]), s0, false);
        if (isFC) op[-kA] = s0;
    }
    if (!isFC) {   // hn, cn (fp32 master state), concatenated after out
        float* hn = out + (size_t)kB * kT * kA;
        hn[(size_t)b * kH + r] = h;
        hn[(size_t)kB * kH + (size_t)b * kH + r] = c;
    }
}

}  // namespace

extern "C" void kernel_launch(void* const* d_in, const int* in_sizes, int n_in,
                              void* d_out, int out_size, void* d_ws, size_t ws_size,
                              hipStream_t stream) {
    (void)in_sizes; (void)n_in; (void)d_ws; (void)ws_size; (void)out_size;
    const float* x    = (const float*)d_in[0];
    const float* W_ih = (const float*)d_in[1];
    const float* W_hh = (const float*)d_in[2];
    const float* b_ih = (const float*)d_in[3];
    const float* b_hh = (const float*)d_in[4];
    const float* W_fc = (const float*)d_in[5];
    const float* b_fc = (const float*)d_in[6];
    float* out = (float*)d_out;
    hipLaunchKernelGGL(lstm_fused_kernel, dim3(kB / 16), dim3(256), 0, stream,
                       x, W_ih, W_hh, b_ih, b_hh, W_fc, b_fc, out);
}